// Round 4
// baseline (75.904 us; speedup 1.0000x reference)
//
#include <hip/hip_runtime.h>
#include <stdint.h>

constexpr int FEAT  = 512;     // feature dim (K)
constexpr int EMB   = 256;     // embed dim   (M)
constexpr int BATCH = 16384;   // batch       (N)
constexpr int NSAMP = 10;
constexpr int NB    = 32;      // batch rows per block
constexpr float SLOPE  = 11.0f / 48.0f;   // RReLU eval slope (1/8+1/3)/2
constexpr float INV_NS = 1.0f / 10.0f;

using f32x4 = __attribute__((ext_vector_type(4))) float;
using frag8 = __attribute__((ext_vector_type(8))) short;  // 8 bf16 (4 VGPRs)

static __device__ __forceinline__ unsigned f2b(float x) {
    // round-to-nearest-even f32 -> bf16 (low 16 bits of result)
    unsigned u = __builtin_bit_cast(unsigned, x);
    return (u + 0x7fffu + ((u >> 16) & 1u)) >> 16;
}
static __device__ __forceinline__ unsigned pk2(float lo, float hi) {
    return f2b(lo) | (f2b(hi) << 16);
}

// One fused kernel: gather+mean -> LDS(bf16, swizzled) -> MFMA GEMM -> RReLU.
// No workspace, no inter-kernel dependencies: every global READ is an
// immutable harness input (features / weight / idx), so no cross-replay
// cache-staleness hazard (the R2 failure class).
__global__ __launch_bounds__(256, 2) void enc_fused(const float* __restrict__ feat,
                                                    const float* __restrict__ wgt,
                                                    const int*   __restrict__ idx,
                                                    float*       __restrict__ out) {
    __shared__ ushort Bs[NB * FEAT];   // 32 KB; row = local batch row, XOR-swizzled bytes

    const int tid = threadIdx.x;
    const int n0  = blockIdx.x * NB;

    // ---------------- phase 1: gather + mean -> Bs ----------------
    {
        const int r   = tid >> 3;          // 0..31 local batch row (8 threads/row)
        const int sub = tid & 7;
        const int* ib = idx + (size_t)(n0 + r) * NSAMP;
        const float* base[NSAMP];
#pragma unroll
        for (int j = 0; j < NSAMP; ++j)
            base[j] = feat + (size_t)ib[j] * FEAT;
        const int swz = (r & 7) << 4;
#pragma unroll
        for (int c = 0; c < 16; ++c) {
            const int col4 = c * 8 + sub;  // float4 index 0..127 within the row
            float sx = 0.f, sy = 0.f, sz = 0.f, sw = 0.f;
#pragma unroll
            for (int j = 0; j < NSAMP; ++j) {
                const float4 v = *reinterpret_cast<const float4*>(base[j] + col4 * 4);
                sx += v.x; sy += v.y; sz += v.z; sw += v.w;
            }
            ushort4 o;
            o.x = (ushort)f2b(sx * INV_NS); o.y = (ushort)f2b(sy * INV_NS);
            o.z = (ushort)f2b(sz * INV_NS); o.w = (ushort)f2b(sw * INV_NS);
            const int kb = (col4 * 8) ^ swz;   // byte offset within row (8B chunk in 16B slot)
            *reinterpret_cast<ushort4*>((char*)Bs + r * (FEAT * 2) + kb) = o;
        }
    }
    __syncthreads();

    // ---------------- phase 2: out[m][n] = W[m,:].Agg[n,:], RReLU ----------------
    const int wv   = tid >> 6;
    const int lane = tid & 63;
    const int l15  = lane & 15, lq = lane >> 4;
    const int mb   = wv * 64;              // waves split M=256 into 4x64

    f32x4 acc[4][2] = {};

#pragma unroll
    for (int k0 = 0; k0 < FEAT; k0 += 32) {
        frag8 af[4], bf[2];
#pragma unroll
        for (int i = 0; i < 4; ++i) {
            const float* wp = wgt + (size_t)(mb + i * 16 + l15) * FEAT + k0 + lq * 8;
            const float4 a0 = *reinterpret_cast<const float4*>(wp);
            const float4 a1 = *reinterpret_cast<const float4*>(wp + 4);
            union { frag8 f; unsigned u[4]; } pk;
            pk.u[0] = pk2(a0.x, a0.y);
            pk.u[1] = pk2(a0.z, a0.w);
            pk.u[2] = pk2(a1.x, a1.y);
            pk.u[3] = pk2(a1.z, a1.w);
            af[i] = pk.f;
        }
#pragma unroll
        for (int j = 0; j < 2; ++j) {
            const int row = j * 16 + l15;
            const int kb  = (k0 * 2 + lq * 16) ^ ((row & 7) << 4);
            bf[j] = *reinterpret_cast<const frag8*>((const char*)Bs + row * (FEAT * 2) + kb);
        }
#pragma unroll
        for (int i = 0; i < 4; ++i)
#pragma unroll
            for (int j = 0; j < 2; ++j)
                acc[i][j] = __builtin_amdgcn_mfma_f32_16x16x32_bf16(af[i], bf[j], acc[i][j], 0, 0, 0);
    }

    // epilogue: C/D layout col=lane&15, row=(lane>>4)*4+q (verified mapping, R1)
#pragma unroll
    for (int i = 0; i < 4; ++i) {
        const int rb = mb + i * 16 + lq * 4;
#pragma unroll
        for (int j = 0; j < 2; ++j) {
            const int col = n0 + j * 16 + l15;
#pragma unroll
            for (int q = 0; q < 4; ++q) {
                float y = acc[i][j][q];
                y = (y >= 0.f) ? y : y * SLOPE;
                out[(size_t)(rb + q) * BATCH + col] = y;
            }
        }
    }
}

extern "C" void kernel_launch(void* const* d_in, const int* in_sizes, int n_in,
                              void* d_out, int out_size, void* d_ws, size_t ws_size,
                              hipStream_t stream) {
    const float* feat = (const float*)d_in[0];
    const float* wgt  = (const float*)d_in[1];
    const int*   idx  = (const int*)d_in[2];
    float*       out  = (float*)d_out;

    enc_fused<<<BATCH / NB, 256, 0, stream>>>(feat, wgt, idx, out);
}

// Round 5
// 68.190 us; speedup vs baseline: 1.1131x; 1.1131x over previous
//
#include <hip/hip_runtime.h>
#include <stdint.h>

constexpr int FEAT  = 512;     // feature dim (K)
constexpr int EMB   = 256;     // embed dim   (M)
constexpr int BATCH = 16384;   // batch       (N)
constexpr int NSAMP = 10;
constexpr int NB    = 64;      // batch rows per block
constexpr float SLOPE  = 11.0f / 48.0f;   // RReLU eval slope (1/8+1/3)/2
constexpr float INV_NS = 1.0f / 10.0f;

using f32x4 = __attribute__((ext_vector_type(4))) float;
using frag8 = __attribute__((ext_vector_type(8))) short;  // 8 bf16 (4 VGPRs)

static __device__ __forceinline__ unsigned f2b(float x) {
    // round-to-nearest-even f32 -> bf16 (low 16 bits of result)
    unsigned u = __builtin_bit_cast(unsigned, x);
    return (u + 0x7fffu + ((u >> 16) & 1u)) >> 16;
}
static __device__ __forceinline__ unsigned pk2(float lo, float hi) {
    return f2b(lo) | (f2b(hi) << 16);
}

// One fused kernel: gather+mean -> LDS(bf16, swizzled) -> MFMA GEMM -> RReLU.
// No workspace: every global READ is an immutable harness input, so no
// cross-replay cache-staleness hazard (R2 failure class).
// NB=64 / grid=256 (1 block/CU): W f32 re-read = 134 MB L2-served (~4 us),
// half of R4's 268 MB which caused the regression.
__global__ __launch_bounds__(512, 2) void enc_fused(const float* __restrict__ feat,
                                                    const float* __restrict__ wgt,
                                                    const int*   __restrict__ idx,
                                                    float*       __restrict__ out) {
    __shared__ ushort Bs[NB * FEAT];   // 64 KB; row-major 1KB rows, XOR-swizzled

    const int tid  = threadIdx.x;
    const int wv   = tid >> 6;
    const int lane = tid & 63;
    const int n0   = blockIdx.x * NB;

    // ---------------- phase 1: gather + mean -> Bs ----------------
    // wave wv owns rows wv*8 .. wv*8+7; lane covers 8 contiguous floats (32B).
#pragma unroll 2
    for (int rr = 0; rr < 8; ++rr) {
        const int r  = wv * 8 + rr;
        const int ru = __builtin_amdgcn_readfirstlane(r);       // -> scalar idx loads
        const int* ib = idx + (size_t)(n0 + ru) * NSAMP;
        f32x4 s0 = {0.f, 0.f, 0.f, 0.f}, s1 = {0.f, 0.f, 0.f, 0.f};
#pragma unroll
        for (int j = 0; j < NSAMP; ++j) {
            const float* fp = feat + (size_t)ib[j] * FEAT + lane * 8;
            const f32x4 v0 = *reinterpret_cast<const f32x4*>(fp);
            const f32x4 v1 = *reinterpret_cast<const f32x4*>(fp + 4);
            s0 += v0; s1 += v1;
        }
        union { frag8 f; unsigned u[4]; } o;
        o.u[0] = pk2(s0[0] * INV_NS, s0[1] * INV_NS);
        o.u[1] = pk2(s0[2] * INV_NS, s0[3] * INV_NS);
        o.u[2] = pk2(s1[0] * INV_NS, s1[1] * INV_NS);
        o.u[3] = pk2(s1[2] * INV_NS, s1[3] * INV_NS);
        const int kb = (lane * 16) ^ ((r & 7) << 4);            // swizzled byte offset
        *reinterpret_cast<frag8*>((char*)Bs + r * (FEAT * 2) + kb) = o.f;
    }
    __syncthreads();

    // ---------------- phase 2: out[m][n] = W[m,:].Agg[n,:], RReLU ----------------
    const int l15 = lane & 15, lq = lane >> 4;
    const int m0w = wv * 32;               // 8 waves split M=256 into 8x32

    f32x4 acc[2][4] = {};

#pragma unroll
    for (int k0 = 0; k0 < FEAT; k0 += 32) {
        frag8 af[2], bf[4];
#pragma unroll
        for (int i = 0; i < 2; ++i) {
            const float* wp = wgt + (size_t)(m0w + i * 16 + l15) * FEAT + k0 + lq * 8;
            const f32x4 a0 = *reinterpret_cast<const f32x4*>(wp);
            const f32x4 a1 = *reinterpret_cast<const f32x4*>(wp + 4);
            union { frag8 f; unsigned u[4]; } pk;
            pk.u[0] = pk2(a0[0], a0[1]);
            pk.u[1] = pk2(a0[2], a0[3]);
            pk.u[2] = pk2(a1[0], a1[1]);
            pk.u[3] = pk2(a1[2], a1[3]);
            af[i] = pk.f;
        }
#pragma unroll
        for (int j = 0; j < 4; ++j) {
            const int row = j * 16 + l15;
            const int kb  = (k0 * 2 + lq * 16) ^ ((row & 7) << 4);
            bf[j] = *reinterpret_cast<const frag8*>((const char*)Bs + row * (FEAT * 2) + kb);
        }
#pragma unroll
        for (int i = 0; i < 2; ++i)
#pragma unroll
            for (int j = 0; j < 4; ++j)
                acc[i][j] = __builtin_amdgcn_mfma_f32_16x16x32_bf16(af[i], bf[j], acc[i][j], 0, 0, 0);
    }

    // epilogue: C/D layout col=lane&15, row=(lane>>4)*4+q (verified mapping)
#pragma unroll
    for (int i = 0; i < 2; ++i) {
        const int rb = m0w + i * 16 + lq * 4;
#pragma unroll
        for (int j = 0; j < 4; ++j) {
            const int col = n0 + j * 16 + l15;
#pragma unroll
            for (int q = 0; q < 4; ++q) {
                float y = acc[i][j][q];
                y = (y >= 0.f) ? y : y * SLOPE;
                out[(size_t)(rb + q) * BATCH + col] = y;
            }
        }
    }
}

extern "C" void kernel_launch(void* const* d_in, const int* in_sizes, int n_in,
                              void* d_out, int out_size, void* d_ws, size_t ws_size,
                              hipStream_t stream) {
    const float* feat = (const float*)d_in[0];
    const float* wgt  = (const float*)d_in[1];
    const int*   idx  = (const int*)d_in[2];
    float*       out  = (float*)d_out;

    enc_fused<<<BATCH / NB, 512, 0, stream>>>(feat, wgt, idx, out);
}